// Round 6
// baseline (548.690 us; speedup 1.0000x reference)
//
#include <hip/hip_runtime.h>
#include <cstdint>
#include <cstddef>

#define CH 128

typedef __attribute__((ext_vector_type(8))) short bf16x8;
typedef __attribute__((ext_vector_type(4))) float f32x4;

__device__ __forceinline__ unsigned short f2bf(float x){
    unsigned int u = __float_as_uint(x);
    u = (u + 0x7FFFu + ((u >> 16) & 1u)) >> 16;   // RNE
    return (unsigned short)u;
}
__device__ __forceinline__ float bf2f(unsigned short b){
    return __uint_as_float(((unsigned int)b) << 16);
}
__device__ __forceinline__ bf16x8 cvt8(float4 a, float4 b){
    union { uint4 u; bf16x8 v; } r;
    r.u.x = (unsigned int)f2bf(a.x) | ((unsigned int)f2bf(a.y) << 16);
    r.u.y = (unsigned int)f2bf(a.z) | ((unsigned int)f2bf(a.w) << 16);
    r.u.z = (unsigned int)f2bf(b.x) | ((unsigned int)f2bf(b.y) << 16);
    r.u.w = (unsigned int)f2bf(b.z) | ((unsigned int)f2bf(b.w) << 16);
    return r.v;
}

// ---------------------------------------------------------------------------
// k0: transpose+convert weights to bf16 wT[mat][n][k]; zero sums[256*256].
// ---------------------------------------------------------------------------
__global__ __launch_bounds__(256) void k0_prep(
        const float* __restrict__ w_self, const float* __restrict__ w_h,
        const float* __restrict__ w_t, unsigned short* __restrict__ wT,
        float* __restrict__ sums){
    int t = blockIdx.x * 256 + threadIdx.x;
    if (t < 256*256) sums[t] = 0.f;
    if (t < 3*CH*CH){
        int mat = t / (CH*CH);
        int r = t - mat*(CH*CH);
        int k = r >> 7, n = r & 127;
        const float* w = (mat == 0) ? w_self : ((mat == 1) ? w_h : w_t);
        wT[mat*CH*CH + n*CH + k] = f2bf(w[k*CH + n]);
    }
}

// ---------------------------------------------------------------------------
// k1: H = x @ w_h, T = x @ w_t  (bf16 out, f32 MFMA accumulate). Proven R0-R5.
// ---------------------------------------------------------------------------
__global__ __launch_bounds__(512) void k1_ht(
        const float* __restrict__ x, const unsigned short* __restrict__ wT,
        unsigned short* __restrict__ H, unsigned short* __restrict__ T, int N){
    __shared__ __align__(16) unsigned char smem[98304];
    const int tid = threadIdx.x;
    const int m0 = blockIdx.x * 128;
    #pragma unroll
    for (int i = 0; i < 8; ++i){
        int g = tid + i*512;
        int row = g >> 5, col4 = (g & 31) * 4;
        int rg = m0 + row; rg = rg < N ? rg : N-1;
        float4 v = *(const float4*)(x + (size_t)rg*CH + col4);
        unsigned int lo = (unsigned int)f2bf(v.x) | ((unsigned int)f2bf(v.y) << 16);
        unsigned int hi = (unsigned int)f2bf(v.z) | ((unsigned int)f2bf(v.w) << 16);
        unsigned int b = ((unsigned int)(row*256 + col4*2)) ^ ((unsigned int)(row & 7) << 4);
        *(uint2*)(smem + b) = make_uint2(lo, hi);
    }
    #pragma unroll
    for (int m = 0; m < 2; ++m){
        const unsigned short* src = wT + (m+1)*CH*CH;
        unsigned char* dst = smem + 32768 + m*32768;
        #pragma unroll
        for (int i = 0; i < 4; ++i){
            int g = tid + i*512;
            int n = g >> 4, k8 = (g & 15) * 8;
            uint4 v = *(const uint4*)(src + n*CH + k8);
            unsigned int b = ((unsigned int)(n*256 + k8*2)) ^ ((unsigned int)(n & 7) << 4);
            *(uint4*)(dst + b) = v;
        }
    }
    __syncthreads();
    const int lane = tid & 63, wv = tid >> 6;
    const int lr = lane & 15, lg = lane >> 4;
    f32x4 accH[8], accT[8];
    #pragma unroll
    for (int n = 0; n < 8; ++n){ accH[n] = (f32x4){0.f,0.f,0.f,0.f}; accT[n] = (f32x4){0.f,0.f,0.f,0.f}; }
    #pragma unroll
    for (int kk = 0; kk < 4; ++kk){
        int arow = wv*16 + lr;
        unsigned int ab = ((unsigned int)(arow*256 + kk*64 + lg*16)) ^ ((unsigned int)(arow & 7) << 4);
        bf16x8 a = *(const bf16x8*)(smem + ab);
        #pragma unroll
        for (int n = 0; n < 8; ++n){
            int cc = n*16 + lr;
            unsigned int bb = ((unsigned int)(cc*256 + kk*64 + lg*16)) ^ ((unsigned int)(cc & 7) << 4);
            bf16x8 bh = *(const bf16x8*)(smem + 32768 + bb);
            bf16x8 bt = *(const bf16x8*)(smem + 65536 + bb);
            accH[n] = __builtin_amdgcn_mfma_f32_16x16x32_bf16(a, bh, accH[n], 0, 0, 0);
            accT[n] = __builtin_amdgcn_mfma_f32_16x16x32_bf16(a, bt, accT[n], 0, 0, 0);
        }
    }
    #pragma unroll
    for (int n = 0; n < 8; ++n){
        int cc = n*16 + lr;
        #pragma unroll
        for (int j = 0; j < 4; ++j){
            int mr = m0 + wv*16 + lg*4 + j;
            if (mr < N){
                H[(size_t)mr*CH + cc] = f2bf(accH[n][j]);
                T[(size_t)mr*CH + cc] = f2bf(accT[n][j]);
            }
        }
    }
}

// ---------------------------------------------------------------------------
// kG: wave-autonomous streaming GEMM. P = ea @ w_self (bf16 out, row-major).
//   One wave per 16-edge tile, grid-stride. NO LDS, NO barriers.
//   A-frags direct from global (verified lane->(row,k) map); B-frags from
//   L1-hot wT. av-wait precedes bw-issue -> no vmcnt cross-drain.
// ---------------------------------------------------------------------------
__global__ __launch_bounds__(256, 4) void kG(
        const float* __restrict__ ea, const unsigned short* __restrict__ wT,
        unsigned short* __restrict__ P, int nt){
    const int wid = (blockIdx.x * 256 + threadIdx.x) >> 6;
    const int nw  = (gridDim.x * 256) >> 6;
    const int lane = threadIdx.x & 63;
    const int lr = lane & 15, lg = lane >> 4;
    for (int t = wid; t < nt; t += nw){
        const size_t e0 = (size_t)t * 16;
        const float* ap = ea + (e0 + lr)*CH;
        float4 av[8];
        #pragma unroll
        for (int kk = 0; kk < 4; ++kk){
            av[kk*2]   = *(const float4*)(ap + kk*32 + lg*8);
            av[kk*2+1] = *(const float4*)(ap + kk*32 + lg*8 + 4);
        }
        bf16x8 af[4];
        #pragma unroll
        for (int kk = 0; kk < 4; ++kk) af[kk] = cvt8(av[kk*2], av[kk*2+1]);
        f32x4 acc[8];
        #pragma unroll
        for (int n = 0; n < 8; ++n) acc[n] = (f32x4){0.f,0.f,0.f,0.f};
        #pragma unroll
        for (int kk = 0; kk < 4; ++kk){
            #pragma unroll
            for (int n = 0; n < 8; ++n){
                bf16x8 bw = *(const bf16x8*)(wT + (size_t)(n*16 + lr)*CH + kk*32 + lg*8);
                acc[n] = __builtin_amdgcn_mfma_f32_16x16x32_bf16(af[kk], bw, acc[n], 0, 0, 0);
            }
        }
        // C/D layout: col = n*16+lr, row = lg*4+j  (HW-verified)
        #pragma unroll
        for (int n = 0; n < 8; ++n){
            #pragma unroll
            for (int j = 0; j < 4; ++j){
                P[(e0 + lg*4 + j)*CH + n*16 + lr] = f2bf(acc[n][j]);
            }
        }
    }
}

// ---------------------------------------------------------------------------
// kE0: fused gather + elementwise + stats. Grid-stride over 16B chunks,
//   NO LDS, NO barriers (k2g/k4 proven style).
//   chunk g: e = g>>4, c8 = (g&15)*8.  v = P*(1+0.5(h+t)) + ea.
//   Writes vb = bf16(v) IN PLACE over P (dead after read).
//   Stats: per-thread fixed 8 channels in regs -> shfl x4 -> atomics.
// ---------------------------------------------------------------------------
__global__ __launch_bounds__(256, 6) void kE0(
        const int* __restrict__ eidx,
        const unsigned short* __restrict__ Hm, const unsigned short* __restrict__ Tm,
        const float* __restrict__ ea, unsigned short* __restrict__ P,
        float* __restrict__ sums, int E){
    const int nth = gridDim.x * 256;          // multiple of 16 -> (g&15) fixed
    const int nchunk = E * 16;
    const int tid0 = blockIdx.x * 256 + threadIdx.x;
    float s[8], ss[8];
    #pragma unroll
    for (int i = 0; i < 8; ++i){ s[i] = 0.f; ss[i] = 0.f; }
    for (int g = tid0; g < nchunk; g += nth){
        int e = g >> 4, c8 = (g & 15) * 8;
        int ri = eidx[e], ci = eidx[E + e];
        uint4 hv = *(const uint4*)(Hm + (size_t)ri*CH + c8);
        uint4 tv = *(const uint4*)(Tm + (size_t)ci*CH + c8);
        uint4 pv = *(const uint4*)(P + (size_t)g*8);
        float4 r0 = *(const float4*)(ea + (size_t)e*CH + c8);
        float4 r1 = *(const float4*)(ea + (size_t)e*CH + c8 + 4);
        float vv[8];
        const unsigned int* hw = (const unsigned int*)&hv;
        const unsigned int* tw = (const unsigned int*)&tv;
        const unsigned int* pw = (const unsigned int*)&pv;
        const float* rr = (const float*)&r0;   // r0,r1 contiguous on stack? no — handle split
        #pragma unroll
        for (int w = 0; w < 4; ++w){
            float h0 = bf2f((unsigned short)(hw[w] & 0xffff));
            float h1 = bf2f((unsigned short)(hw[w] >> 16));
            float t0 = bf2f((unsigned short)(tw[w] & 0xffff));
            float t1 = bf2f((unsigned short)(tw[w] >> 16));
            float p0 = bf2f((unsigned short)(pw[w] & 0xffff));
            float p1 = bf2f((unsigned short)(pw[w] >> 16));
            float ra = (w < 2) ? ((w & 1) ? r0.z : r0.x) : ((w & 1) ? r1.z : r1.x);
            float rb = (w < 2) ? ((w & 1) ? r0.w : r0.y) : ((w & 1) ? r1.w : r1.y);
            vv[w*2]   = fmaf(p0, 0.5f*(h0 + t0), p0) + ra;
            vv[w*2+1] = fmaf(p1, 0.5f*(h1 + t1), p1) + rb;
        }
        (void)rr;
        uint4 vb;
        vb.x = (unsigned int)f2bf(vv[0]) | ((unsigned int)f2bf(vv[1]) << 16);
        vb.y = (unsigned int)f2bf(vv[2]) | ((unsigned int)f2bf(vv[3]) << 16);
        vb.z = (unsigned int)f2bf(vv[4]) | ((unsigned int)f2bf(vv[5]) << 16);
        vb.w = (unsigned int)f2bf(vv[6]) | ((unsigned int)f2bf(vv[7]) << 16);
        *(uint4*)(P + (size_t)g*8) = vb;
        #pragma unroll
        for (int i = 0; i < 8; ++i){ s[i] += vv[i]; ss[i] += vv[i]*vv[i]; }
    }
    // lanes l, l^16, l^32, l^48 share the same channel set (nth % 16 == 0)
    const int lane = threadIdx.x & 63;
    #pragma unroll
    for (int i = 0; i < 8; ++i){
        s[i]  += __shfl_xor(s[i], 16);  s[i]  += __shfl_xor(s[i], 32);
        ss[i] += __shfl_xor(ss[i], 16); ss[i] += __shfl_xor(ss[i], 32);
    }
    if (lane < 16){
        float* slot = sums + (size_t)(blockIdx.x & 255)*256;
        #pragma unroll
        for (int i = 0; i < 8; ++i){
            atomicAdd(&slot[lane*8 + i], s[i]);
            atomicAdd(&slot[CH + lane*8 + i], ss[i]);
        }
    }
}

// ---------------------------------------------------------------------------
// k3: reduce 256 slots -> per-channel scale/shift (sb)
// ---------------------------------------------------------------------------
__global__ __launch_bounds__(128) void k3_stats(
        const float* __restrict__ sums, const float* __restrict__ gamma,
        const float* __restrict__ beta, float* __restrict__ sb, float invE){
    int c = threadIdx.x;
    float s = 0.f, ss = 0.f;
    for (int i = 0; i < 256; ++i){ s += sums[i*256 + c]; ss += sums[i*256 + CH + c]; }
    float mean = s * invE;
    float var = ss * invE - mean*mean;     // biased variance (matches reference)
    float inv = rsqrtf(var + 1e-5f);
    float sc = gamma[c] * inv;
    sb[c] = sc;
    sb[CH + c] = beta[c] - mean * sc;
}

// ---------------------------------------------------------------------------
// kE1: out_f32 = relu(vb*scale + shift); 8 elems/thread (R1's proven k4_bf16)
// ---------------------------------------------------------------------------
__global__ __launch_bounds__(256) void kE1(
        const unsigned short* __restrict__ vb, const float* __restrict__ sb,
        float* __restrict__ out, int n8){
    int i = blockIdx.x * 256 + threadIdx.x;
    int stride = gridDim.x * 256;
    const uint4* v8 = (const uint4*)vb;
    for (; i < n8; i += stride){
        uint4 v = v8[i];
        int c8 = (i & 15) * 8;
        float4 sc0 = *(const float4*)(sb + c8);
        float4 sc1 = *(const float4*)(sb + c8 + 4);
        float4 sh0 = *(const float4*)(sb + CH + c8);
        float4 sh1 = *(const float4*)(sb + CH + c8 + 4);
        float4 o0, o1;
        o0.x = fmaxf(fmaf(bf2f((unsigned short)(v.x & 0xffff)), sc0.x, sh0.x), 0.f);
        o0.y = fmaxf(fmaf(bf2f((unsigned short)(v.x >> 16)),    sc0.y, sh0.y), 0.f);
        o0.z = fmaxf(fmaf(bf2f((unsigned short)(v.y & 0xffff)), sc0.z, sh0.z), 0.f);
        o0.w = fmaxf(fmaf(bf2f((unsigned short)(v.y >> 16)),    sc0.w, sh0.w), 0.f);
        o1.x = fmaxf(fmaf(bf2f((unsigned short)(v.z & 0xffff)), sc1.x, sh1.x), 0.f);
        o1.y = fmaxf(fmaf(bf2f((unsigned short)(v.z >> 16)),    sc1.y, sh1.y), 0.f);
        o1.z = fmaxf(fmaf(bf2f((unsigned short)(v.w & 0xffff)), sc1.z, sh1.z), 0.f);
        o1.w = fmaxf(fmaf(bf2f((unsigned short)(v.w >> 16)),    sc1.w, sh1.w), 0.f);
        *(float4*)(out + (size_t)i*8)     = o0;
        *(float4*)(out + (size_t)i*8 + 4) = o1;
    }
}

extern "C" void kernel_launch(void* const* d_in, const int* in_sizes, int n_in,
                              void* d_out, int out_size, void* d_ws, size_t ws_size,
                              hipStream_t stream) {
    const float* x      = (const float*)d_in[0];
    const int*   eidx   = (const int*)d_in[1];
    const float* ea     = (const float*)d_in[2];
    const float* w_self = (const float*)d_in[4];
    const float* w_h    = (const float*)d_in[5];
    const float* w_t    = (const float*)d_in[6];
    const float* gamma  = (const float*)d_in[7];
    const float* beta   = (const float*)d_in[8];
    float* out = (float*)d_out;

    const int N = in_sizes[0] / CH;     // 40000
    const int E = in_sizes[3];          // 640000

    // workspace carve-up (~185 MB total — R5's big path executed, so it fits):
    float* sums = (float*)d_ws;                          // 256*256 f32
    float* sb   = sums + 256*256;                        // 256 f32
    unsigned short* wT = (unsigned short*)(sb + 256);    // 3*128*128 bf16
    unsigned short* H  = wT + 3*CH*CH;                   // N*128 bf16
    unsigned short* T  = H + (size_t)N*CH;               // N*128 bf16
    unsigned short* P  = T + (size_t)N*CH;               // E*128 bf16 (P, then vb in place)

    k0_prep<<<256, 256, 0, stream>>>(w_self, w_h, w_t, wT, sums);
    k1_ht  <<<(N + 127)/128, 512, 0, stream>>>(x, wT, H, T, N);
    kG     <<<2048, 256, 0, stream>>>(ea, wT, P, E/16);
    kE0    <<<2048, 256, 0, stream>>>(eidx, H, T, ea, P, sums, E);
    k3_stats<<<1, 128, 0, stream>>>(sums, gamma, beta, sb, 1.0f/(float)E);
    kE1    <<<2048, 256, 0, stream>>>(P, sb, out, E*CH/8);
}

// Round 7
// 457.339 us; speedup vs baseline: 1.1997x; 1.1997x over previous
//
#include <hip/hip_runtime.h>
#include <cstdint>
#include <cstddef>

#define CH 128

typedef __attribute__((ext_vector_type(8))) short bf16x8;
typedef __attribute__((ext_vector_type(4))) float f32x4;

__device__ __forceinline__ unsigned short f2bf(float x){
    unsigned int u = __float_as_uint(x);
    u = (u + 0x7FFFu + ((u >> 16) & 1u)) >> 16;   // RNE
    return (unsigned short)u;
}
__device__ __forceinline__ float bf2f(unsigned short b){
    return __uint_as_float(((unsigned int)b) << 16);
}
__device__ __forceinline__ unsigned int pairadd_bf(unsigned int a, unsigned int b){
    float lo = bf2f((unsigned short)(a & 0xffff)) + bf2f((unsigned short)(b & 0xffff));
    float hi = bf2f((unsigned short)(a >> 16))    + bf2f((unsigned short)(b >> 16));
    return (unsigned int)f2bf(lo) | ((unsigned int)f2bf(hi) << 16);
}
__device__ __forceinline__ bf16x8 cvt8(float4 a, float4 b){
    union { uint4 u; bf16x8 v; } r;
    r.u.x = (unsigned int)f2bf(a.x) | ((unsigned int)f2bf(a.y) << 16);
    r.u.y = (unsigned int)f2bf(a.z) | ((unsigned int)f2bf(a.w) << 16);
    r.u.z = (unsigned int)f2bf(b.x) | ((unsigned int)f2bf(b.y) << 16);
    r.u.w = (unsigned int)f2bf(b.z) | ((unsigned int)f2bf(b.w) << 16);
    return r.v;
}

// ---------------------------------------------------------------------------
// k0: transpose+convert weights to bf16 wT[mat][n][k]; zero sums[256*256].
// ---------------------------------------------------------------------------
__global__ __launch_bounds__(256) void k0_prep(
        const float* __restrict__ w_self, const float* __restrict__ w_h,
        const float* __restrict__ w_t, unsigned short* __restrict__ wT,
        float* __restrict__ sums){
    int t = blockIdx.x * 256 + threadIdx.x;
    if (t < 256*256) sums[t] = 0.f;
    if (t < 3*CH*CH){
        int mat = t / (CH*CH);
        int r = t - mat*(CH*CH);
        int k = r >> 7, n = r & 127;
        const float* w = (mat == 0) ? w_self : ((mat == 1) ? w_h : w_t);
        wT[mat*CH*CH + n*CH + k] = f2bf(w[k*CH + n]);
    }
}

// ---------------------------------------------------------------------------
// k1: H = x @ w_h, T = x @ w_t  (bf16 out, f32 MFMA accumulate). Proven R0-R6.
// ---------------------------------------------------------------------------
__global__ __launch_bounds__(512) void k1_ht(
        const float* __restrict__ x, const unsigned short* __restrict__ wT,
        unsigned short* __restrict__ H, unsigned short* __restrict__ T, int N){
    __shared__ __align__(16) unsigned char smem[98304];
    const int tid = threadIdx.x;
    const int m0 = blockIdx.x * 128;
    #pragma unroll
    for (int i = 0; i < 8; ++i){
        int g = tid + i*512;
        int row = g >> 5, col4 = (g & 31) * 4;
        int rg = m0 + row; rg = rg < N ? rg : N-1;
        float4 v = *(const float4*)(x + (size_t)rg*CH + col4);
        unsigned int lo = (unsigned int)f2bf(v.x) | ((unsigned int)f2bf(v.y) << 16);
        unsigned int hi = (unsigned int)f2bf(v.z) | ((unsigned int)f2bf(v.w) << 16);
        unsigned int b = ((unsigned int)(row*256 + col4*2)) ^ ((unsigned int)(row & 7) << 4);
        *(uint2*)(smem + b) = make_uint2(lo, hi);
    }
    #pragma unroll
    for (int m = 0; m < 2; ++m){
        const unsigned short* src = wT + (m+1)*CH*CH;
        unsigned char* dst = smem + 32768 + m*32768;
        #pragma unroll
        for (int i = 0; i < 4; ++i){
            int g = tid + i*512;
            int n = g >> 4, k8 = (g & 15) * 8;
            uint4 v = *(const uint4*)(src + n*CH + k8);
            unsigned int b = ((unsigned int)(n*256 + k8*2)) ^ ((unsigned int)(n & 7) << 4);
            *(uint4*)(dst + b) = v;
        }
    }
    __syncthreads();
    const int lane = tid & 63, wv = tid >> 6;
    const int lr = lane & 15, lg = lane >> 4;
    f32x4 accH[8], accT[8];
    #pragma unroll
    for (int n = 0; n < 8; ++n){ accH[n] = (f32x4){0.f,0.f,0.f,0.f}; accT[n] = (f32x4){0.f,0.f,0.f,0.f}; }
    #pragma unroll
    for (int kk = 0; kk < 4; ++kk){
        int arow = wv*16 + lr;
        unsigned int ab = ((unsigned int)(arow*256 + kk*64 + lg*16)) ^ ((unsigned int)(arow & 7) << 4);
        bf16x8 a = *(const bf16x8*)(smem + ab);
        #pragma unroll
        for (int n = 0; n < 8; ++n){
            int cc = n*16 + lr;
            unsigned int bb = ((unsigned int)(cc*256 + kk*64 + lg*16)) ^ ((unsigned int)(cc & 7) << 4);
            bf16x8 bh = *(const bf16x8*)(smem + 32768 + bb);
            bf16x8 bt = *(const bf16x8*)(smem + 65536 + bb);
            accH[n] = __builtin_amdgcn_mfma_f32_16x16x32_bf16(a, bh, accH[n], 0, 0, 0);
            accT[n] = __builtin_amdgcn_mfma_f32_16x16x32_bf16(a, bt, accT[n], 0, 0, 0);
        }
    }
    #pragma unroll
    for (int n = 0; n < 8; ++n){
        int cc = n*16 + lr;
        #pragma unroll
        for (int j = 0; j < 4; ++j){
            int mr = m0 + wv*16 + lg*4 + j;
            if (mr < N){
                H[(size_t)mr*CH + cc] = f2bf(accH[n][j]);
                T[(size_t)mr*CH + cc] = f2bf(accT[n][j]);
            }
        }
    }
}

// ---------------------------------------------------------------------------
// kF: fused wave-autonomous main pass. Per 16-edge tile per wave:
//   ea coalesced -> af regs (A-frag + residual); H/T gathered as 64B lines;
//   MFMA (B from L1-hot wT); all layout transposes via wave-PRIVATE LDS
//   slices (u | r | vb) -- NO barriers, NO scalar global access anywhere.
//   vb slice read back as uint4 -> fully coalesced 16B stores to VB.
//   Stats accumulated in regs across tiles, flushed once per wave.
// ---------------------------------------------------------------------------
__global__ __launch_bounds__(256, 3) void kF(
        const float* __restrict__ ea, const int* __restrict__ eidx,
        const unsigned short* __restrict__ wT,
        const unsigned short* __restrict__ Hm, const unsigned short* __restrict__ Tm,
        unsigned short* __restrict__ VB, float* __restrict__ sums, int E, int nt){
    __shared__ __align__(16) unsigned char smem[49152];   // 4 waves x 12KB
    const int tid = threadIdx.x;
    const int lane = tid & 63, wv = tid >> 6;
    unsigned char* su = smem + wv*12288;        // u  = h+t   (4KB)
    unsigned char* sr = su + 4096;              // residual   (4KB)
    unsigned char* sv = sr + 4096;              // v out      (4KB)
    const int lr = lane & 15, lg = lane >> 4;
    const int gr = lane >> 2;                   // gather row 0..15
    const int gc = lane & 3;                    // gather chunk group 0..3
    const int wid = (blockIdx.x*256 + tid) >> 6;
    const int nw  = (gridDim.x*256) >> 6;

    float s[8], ss[8];
    #pragma unroll
    for (int n = 0; n < 8; ++n){ s[n] = 0.f; ss[n] = 0.f; }

    for (int t = wid; t < nt; t += nw){
        const size_t e0 = (size_t)t*16;
        // edge indices (4 lanes per row -> coalesced)
        int ri = eidx[e0 + gr];
        int ci = eidx[E + e0 + gr];
        // A loads: 8 x dwordx4, fully coalesced (wave covers 16 rows x 512B)
        const float* ap = ea + (e0 + lr)*CH;
        float4 av[8];
        #pragma unroll
        for (int kk = 0; kk < 4; ++kk){
            av[kk*2]   = *(const float4*)(ap + kk*32 + lg*8);
            av[kk*2+1] = *(const float4*)(ap + kk*32 + lg*8 + 4);
        }
        // H/T gathers: per i, wave reads 16 rows x 64B contiguous (full lines)
        uint4 hv[4], tv[4];
        #pragma unroll
        for (int i = 0; i < 4; ++i){
            int ch = gc + i*4;
            hv[i] = *(const uint4*)(Hm + (size_t)ri*CH + ch*8);
            tv[i] = *(const uint4*)(Tm + (size_t)ci*CH + ch*8);
        }
        // convert A; write residual slice (bf16)
        bf16x8 af[4];
        #pragma unroll
        for (int kk = 0; kk < 4; ++kk){
            af[kk] = cvt8(av[kk*2], av[kk*2+1]);
            unsigned int b = ((unsigned int)(lr*256 + kk*64 + lg*16)) ^ ((unsigned int)(lr & 7) << 4);
            *(bf16x8*)(sr + b) = af[kk];
        }
        // u = h + t -> u slice
        #pragma unroll
        for (int i = 0; i < 4; ++i){
            uint4 u4;
            u4.x = pairadd_bf(hv[i].x, tv[i].x);
            u4.y = pairadd_bf(hv[i].y, tv[i].y);
            u4.z = pairadd_bf(hv[i].z, tv[i].z);
            u4.w = pairadd_bf(hv[i].w, tv[i].w);
            unsigned int b = ((unsigned int)(gr*256 + (gc + i*4)*16)) ^ ((unsigned int)(gr & 7) << 4);
            *(uint4*)(su + b) = u4;
        }
        // MFMA: out0 = A @ w_self, B-frags from L1-hot wT
        f32x4 acc[8];
        #pragma unroll
        for (int n = 0; n < 8; ++n) acc[n] = (f32x4){0.f,0.f,0.f,0.f};
        #pragma unroll
        for (int kk = 0; kk < 4; ++kk){
            #pragma unroll
            for (int n = 0; n < 8; ++n){
                bf16x8 bw = *(const bf16x8*)(wT + (size_t)(n*16 + lr)*CH + kk*32 + lg*8);
                acc[n] = __builtin_amdgcn_mfma_f32_16x16x32_bf16(af[kk], bw, acc[n], 0, 0, 0);
            }
        }
        // epilogue: C/D layout col=n*16+lr, row=lg*4+j (HW-verified).
        // wave-private LDS => compiler-ordered lgkmcnt, no barrier.
        #pragma unroll
        for (int n = 0; n < 8; ++n){
            int cc = n*16 + lr;
            #pragma unroll
            for (int j = 0; j < 4; ++j){
                int row = lg*4 + j;
                unsigned int b = ((unsigned int)(row*256 + cc*2)) ^ ((unsigned int)(row & 7) << 4);
                float u = bf2f(*(const unsigned short*)(su + b));
                float r = bf2f(*(const unsigned short*)(sr + b));
                float o0 = acc[n][j];
                float v = fmaf(o0, 0.5f*u, o0) + r;   // o0*(1+0.5(h+t)) + ea
                *(unsigned short*)(sv + b) = f2bf(v);
                s[n] += v; ss[n] += v*v;
            }
        }
        // readback vb slice -> fully coalesced 16B global stores
        #pragma unroll
        for (int i = 0; i < 4; ++i){
            unsigned int b = ((unsigned int)(gr*256 + (gc + i*4)*16)) ^ ((unsigned int)(gr & 7) << 4);
            uint4 o = *(const uint4*)(sv + b);
            *(uint4*)(VB + (e0 + gr)*CH + (gc + i*4)*8) = o;
        }
    }
    // stats flush: lanes sharing lr hold same channel set {n*16+lr}
    #pragma unroll
    for (int n = 0; n < 8; ++n){
        s[n]  += __shfl_xor(s[n], 16);  s[n]  += __shfl_xor(s[n], 32);
        ss[n] += __shfl_xor(ss[n], 16); ss[n] += __shfl_xor(ss[n], 32);
    }
    if (lane < 16){
        float* slot = sums + (size_t)((blockIdx.x*4 + wv) & 255)*256;
        #pragma unroll
        for (int n = 0; n < 8; ++n){
            atomicAdd(&slot[n*16 + lane], s[n]);
            atomicAdd(&slot[CH + n*16 + lane], ss[n]);
        }
    }
}

// ---------------------------------------------------------------------------
// k3: reduce 256 slots -> per-channel scale/shift (sb)
// ---------------------------------------------------------------------------
__global__ __launch_bounds__(128) void k3_stats(
        const float* __restrict__ sums, const float* __restrict__ gamma,
        const float* __restrict__ beta, float* __restrict__ sb, float invE){
    int c = threadIdx.x;
    float s = 0.f, ss = 0.f;
    for (int i = 0; i < 256; ++i){ s += sums[i*256 + c]; ss += sums[i*256 + CH + c]; }
    float mean = s * invE;
    float var = ss * invE - mean*mean;     // biased variance (matches reference)
    float inv = rsqrtf(var + 1e-5f);
    float sc = gamma[c] * inv;
    sb[c] = sc;
    sb[CH + c] = beta[c] - mean * sc;
}

// ---------------------------------------------------------------------------
// kE1: out_f32 = relu(vb*scale + shift); 8 elems/thread (proven)
// ---------------------------------------------------------------------------
__global__ __launch_bounds__(256) void kE1(
        const unsigned short* __restrict__ vb, const float* __restrict__ sb,
        float* __restrict__ out, int n8){
    int i = blockIdx.x * 256 + threadIdx.x;
    int stride = gridDim.x * 256;
    const uint4* v8 = (const uint4*)vb;
    for (; i < n8; i += stride){
        uint4 v = v8[i];
        int c8 = (i & 15) * 8;
        float4 sc0 = *(const float4*)(sb + c8);
        float4 sc1 = *(const float4*)(sb + c8 + 4);
        float4 sh0 = *(const float4*)(sb + CH + c8);
        float4 sh1 = *(const float4*)(sb + CH + c8 + 4);
        float4 o0, o1;
        o0.x = fmaxf(fmaf(bf2f((unsigned short)(v.x & 0xffff)), sc0.x, sh0.x), 0.f);
        o0.y = fmaxf(fmaf(bf2f((unsigned short)(v.x >> 16)),    sc0.y, sh0.y), 0.f);
        o0.z = fmaxf(fmaf(bf2f((unsigned short)(v.y & 0xffff)), sc0.z, sh0.z), 0.f);
        o0.w = fmaxf(fmaf(bf2f((unsigned short)(v.y >> 16)),    sc0.w, sh0.w), 0.f);
        o1.x = fmaxf(fmaf(bf2f((unsigned short)(v.z & 0xffff)), sc1.x, sh1.x), 0.f);
        o1.y = fmaxf(fmaf(bf2f((unsigned short)(v.z >> 16)),    sc1.y, sh1.y), 0.f);
        o1.z = fmaxf(fmaf(bf2f((unsigned short)(v.w & 0xffff)), sc1.z, sh1.z), 0.f);
        o1.w = fmaxf(fmaf(bf2f((unsigned short)(v.w >> 16)),    sc1.w, sh1.w), 0.f);
        *(float4*)(out + (size_t)i*8)     = o0;
        *(float4*)(out + (size_t)i*8 + 4) = o1;
    }
}

extern "C" void kernel_launch(void* const* d_in, const int* in_sizes, int n_in,
                              void* d_out, int out_size, void* d_ws, size_t ws_size,
                              hipStream_t stream) {
    const float* x      = (const float*)d_in[0];
    const int*   eidx   = (const int*)d_in[1];
    const float* ea     = (const float*)d_in[2];
    const float* w_self = (const float*)d_in[4];
    const float* w_h    = (const float*)d_in[5];
    const float* w_t    = (const float*)d_in[6];
    const float* gamma  = (const float*)d_in[7];
    const float* beta   = (const float*)d_in[8];
    float* out = (float*)d_out;

    const int N = in_sizes[0] / CH;     // 40000
    const int E = in_sizes[3];          // 640000

    // workspace carve-up (~185 MB total — proven to fit in R5/R6):
    float* sums = (float*)d_ws;                          // 256*256 f32
    float* sb   = sums + 256*256;                        // 256 f32
    unsigned short* wT = (unsigned short*)(sb + 256);    // 3*128*128 bf16
    unsigned short* H  = wT + 3*CH*CH;                   // N*128 bf16
    unsigned short* T  = H + (size_t)N*CH;               // N*128 bf16
    unsigned short* VB = T + (size_t)N*CH;               // E*128 bf16 pre-BN

    k0_prep<<<256, 256, 0, stream>>>(w_self, w_h, w_t, wT, sums);
    k1_ht  <<<(N + 127)/128, 512, 0, stream>>>(x, wT, H, T, N);
    kF     <<<2048, 256, 0, stream>>>(ea, eidx, wT, H, T, VB, sums, E, E/16);
    k3_stats<<<1, 128, 0, stream>>>(sums, gamma, beta, sb, 1.0f/(float)E);
    kE1    <<<2048, 256, 0, stream>>>(VB, sb, out, E*CH/8);
}

// Round 8
// 384.035 us; speedup vs baseline: 1.4288x; 1.1909x over previous
//
#include <hip/hip_runtime.h>
#include <cstdint>
#include <cstddef>

#define CH 128

typedef __attribute__((ext_vector_type(8))) short bf16x8;
typedef __attribute__((ext_vector_type(4))) float f32x4;

__device__ __forceinline__ unsigned short f2bf(float x){
    unsigned int u = __float_as_uint(x);
    u = (u + 0x7FFFu + ((u >> 16) & 1u)) >> 16;   // RNE
    return (unsigned short)u;
}
__device__ __forceinline__ float bf2f(unsigned short b){
    return __uint_as_float(((unsigned int)b) << 16);
}

// ---------------------------------------------------------------------------
// k0: transpose+convert weights to bf16 wT[mat][n][k]; zero sums[256*256].
// ---------------------------------------------------------------------------
__global__ __launch_bounds__(256) void k0_prep(
        const float* __restrict__ w_self, const float* __restrict__ w_h,
        const float* __restrict__ w_t, unsigned short* __restrict__ wT,
        float* __restrict__ sums){
    int t = blockIdx.x * 256 + threadIdx.x;
    if (t < 256*256) sums[t] = 0.f;
    if (t < 3*CH*CH){
        int mat = t / (CH*CH);
        int r = t - mat*(CH*CH);
        int k = r >> 7, n = r & 127;
        const float* w = (mat == 0) ? w_self : ((mat == 1) ? w_h : w_t);
        wT[mat*CH*CH + n*CH + k] = f2bf(w[k*CH + n]);
    }
}

// ---------------------------------------------------------------------------
// k1: H = x @ w_h, T = x @ w_t  (bf16 out, f32 MFMA accumulate). Proven R0-R7.
// ---------------------------------------------------------------------------
__global__ __launch_bounds__(512) void k1_ht(
        const float* __restrict__ x, const unsigned short* __restrict__ wT,
        unsigned short* __restrict__ H, unsigned short* __restrict__ T, int N){
    __shared__ __align__(16) unsigned char smem[98304];
    const int tid = threadIdx.x;
    const int m0 = blockIdx.x * 128;
    #pragma unroll
    for (int i = 0; i < 8; ++i){
        int g = tid + i*512;
        int row = g >> 5, col4 = (g & 31) * 4;
        int rg = m0 + row; rg = rg < N ? rg : N-1;
        float4 v = *(const float4*)(x + (size_t)rg*CH + col4);
        unsigned int lo = (unsigned int)f2bf(v.x) | ((unsigned int)f2bf(v.y) << 16);
        unsigned int hi = (unsigned int)f2bf(v.z) | ((unsigned int)f2bf(v.w) << 16);
        unsigned int b = ((unsigned int)(row*256 + col4*2)) ^ ((unsigned int)(row & 7) << 4);
        *(uint2*)(smem + b) = make_uint2(lo, hi);
    }
    #pragma unroll
    for (int m = 0; m < 2; ++m){
        const unsigned short* src = wT + (m+1)*CH*CH;
        unsigned char* dst = smem + 32768 + m*32768;
        #pragma unroll
        for (int i = 0; i < 4; ++i){
            int g = tid + i*512;
            int n = g >> 4, k8 = (g & 15) * 8;
            uint4 v = *(const uint4*)(src + n*CH + k8);
            unsigned int b = ((unsigned int)(n*256 + k8*2)) ^ ((unsigned int)(n & 7) << 4);
            *(uint4*)(dst + b) = v;
        }
    }
    __syncthreads();
    const int lane = tid & 63, wv = tid >> 6;
    const int lr = lane & 15, lg = lane >> 4;
    f32x4 accH[8], accT[8];
    #pragma unroll
    for (int n = 0; n < 8; ++n){ accH[n] = (f32x4){0.f,0.f,0.f,0.f}; accT[n] = (f32x4){0.f,0.f,0.f,0.f}; }
    #pragma unroll
    for (int kk = 0; kk < 4; ++kk){
        int arow = wv*16 + lr;
        unsigned int ab = ((unsigned int)(arow*256 + kk*64 + lg*16)) ^ ((unsigned int)(arow & 7) << 4);
        bf16x8 a = *(const bf16x8*)(smem + ab);
        #pragma unroll
        for (int n = 0; n < 8; ++n){
            int cc = n*16 + lr;
            unsigned int bb = ((unsigned int)(cc*256 + kk*64 + lg*16)) ^ ((unsigned int)(cc & 7) << 4);
            bf16x8 bh = *(const bf16x8*)(smem + 32768 + bb);
            bf16x8 bt = *(const bf16x8*)(smem + 65536 + bb);
            accH[n] = __builtin_amdgcn_mfma_f32_16x16x32_bf16(a, bh, accH[n], 0, 0, 0);
            accT[n] = __builtin_amdgcn_mfma_f32_16x16x32_bf16(a, bt, accT[n], 0, 0, 0);
        }
    }
    #pragma unroll
    for (int n = 0; n < 8; ++n){
        int cc = n*16 + lr;
        #pragma unroll
        for (int j = 0; j < 4; ++j){
            int mr = m0 + wv*16 + lg*4 + j;
            if (mr < N){
                H[(size_t)mr*CH + cc] = f2bf(accH[n][j]);
                T[(size_t)mr*CH + cc] = f2bf(accT[n][j]);
            }
        }
    }
}

// ---------------------------------------------------------------------------
// k2v: R1's proven k2_main (287us) with ONE change: output goes through an
//   LDS redistribute (bf16 v written in-place over the h-region, +1 barrier)
//   and is stored fully-coalesced as bf16 VB (164 MB vs 404 MB f32 scatter).
//   Everything else identical: contiguous ea staging, wT+A in LDS, 4-seg
//   gathers, residual from staged A, per-block stats partials.
// ---------------------------------------------------------------------------
__global__ __launch_bounds__(512, 4) void k2v(
        const float* __restrict__ ea, const int* __restrict__ eidx,
        const unsigned short* __restrict__ wT,
        const unsigned short* __restrict__ Hm, const unsigned short* __restrict__ Tm,
        unsigned short* __restrict__ VB, float* __restrict__ sums, int E){
    __shared__ __align__(16) unsigned char smem[66560];
    float* red = (float*)(smem + 65536);
    const int tid = threadIdx.x;
    const int e0 = blockIdx.x * 128;
    if (tid < 256) red[tid] = 0.f;

    // ---- issue streaming ea loads first (contiguous 512B-row g-pattern) ----
    float4 eav[8];
    #pragma unroll
    for (int i = 0; i < 8; ++i){
        int g = tid + i*512;
        int row = g >> 5, col4 = (g & 31)*4;
        eav[i] = *(const float4*)(ea + (size_t)(e0+row)*CH + col4);
    }
    // ---- weight tile loads (L2-hot) ----
    uint4 wv4[4];
    #pragma unroll
    for (int i = 0; i < 4; ++i){
        int g = tid + i*512;
        int n = g >> 4, k8 = (g & 15)*8;
        wv4[i] = *(const uint4*)(wT + n*CH + k8);
    }
    // ---- edge indices, then 4-seg x 256B gathers of H/T ----
    int ri4[4], ci4[4];
    #pragma unroll
    for (int i = 0; i < 4; ++i){
        int r = (tid + i*512) >> 4;
        ri4[i] = eidx[e0 + r];
        ci4[i] = eidx[E + e0 + r];
    }
    uint4 hv[4], tv[4];
    #pragma unroll
    for (int i = 0; i < 4; ++i){
        int c = (tid + i*512) & 15;
        hv[i] = *(const uint4*)(Hm + (size_t)ri4[i]*CH + c*8);
        tv[i] = *(const uint4*)(Tm + (size_t)ci4[i]*CH + c*8);
    }
    // ---- stage ea -> bf16 LDS A-region (row-swizzle <<4) ----
    #pragma unroll
    for (int i = 0; i < 8; ++i){
        int g = tid + i*512;
        int row = g >> 5, col4 = (g & 31)*4;
        float4 v = eav[i];
        unsigned int lo = (unsigned int)f2bf(v.x) | ((unsigned int)f2bf(v.y) << 16);
        unsigned int hi = (unsigned int)f2bf(v.z) | ((unsigned int)f2bf(v.w) << 16);
        unsigned int b = ((unsigned int)(row*256 + col4*2)) ^ ((unsigned int)(row & 7) << 4);
        *(uint2*)(smem + b) = make_uint2(lo, hi);
    }
    // ---- stage weights -> LDS B-region ----
    #pragma unroll
    for (int i = 0; i < 4; ++i){
        int g = tid + i*512;
        int n = g >> 4, k8 = (g & 15)*8;
        unsigned int b = ((unsigned int)(n*256 + k8*2)) ^ ((unsigned int)(n & 7) << 4);
        *(uint4*)(smem + 32768 + b) = wv4[i];
    }
    __syncthreads();                                   // B1

    const int lane = tid & 63, wv = tid >> 6;
    const int lr = lane & 15, lg = lane >> 4;
    f32x4 acc[8];
    #pragma unroll
    for (int n = 0; n < 8; ++n) acc[n] = (f32x4){0.f,0.f,0.f,0.f};
    #pragma unroll
    for (int kk = 0; kk < 4; ++kk){
        int arow = wv*16 + lr;
        unsigned int ab = ((unsigned int)(arow*256 + kk*64 + lg*16)) ^ ((unsigned int)(arow & 7) << 4);
        bf16x8 a = *(const bf16x8*)(smem + ab);
        #pragma unroll
        for (int n = 0; n < 8; ++n){
            int cc = n*16 + lr;
            unsigned int bb = ((unsigned int)(cc*256 + kk*64 + lg*16)) ^ ((unsigned int)(cc & 7) << 4);
            bf16x8 bw = *(const bf16x8*)(smem + 32768 + bb);
            acc[n] = __builtin_amdgcn_mfma_f32_16x16x32_bf16(a, bw, acc[n], 0, 0, 0);
        }
    }
    // ---- residual: read staged ea (bf16) before overwrite ----
    float res[32];
    #pragma unroll
    for (int n = 0; n < 8; ++n){
        int cc = n*16 + lr;
        #pragma unroll
        for (int j = 0; j < 4; ++j){
            int ml = wv*16 + lg*4 + j;
            unsigned int b = ((unsigned int)(ml*256 + cc*2)) ^ ((unsigned int)(ml & 7) << 4);
            res[n*4 + j] = bf2f(*(const unsigned short*)(smem + b));
        }
    }
    __syncthreads();                                   // B2: A/B LDS free
    // ---- redistribute gathered H/T rows (octet swizzle on bits 6:5) ----
    #pragma unroll
    for (int i = 0; i < 4; ++i){
        int g = tid + i*512;
        int r = g >> 4, c = g & 15;
        unsigned int b = ((unsigned int)(r*256 + c*16)) ^ ((unsigned int)((r >> 2) & 3) << 5);
        *(uint4*)(smem + b) = hv[i];
        *(uint4*)(smem + 32768 + b) = tv[i];
    }
    __syncthreads();                                   // B3
    // ---- epilogue: v = o0*(1+0.5(h+t)) + res; stats; bf16 v in-place over h
    #pragma unroll
    for (int n = 0; n < 8; ++n){
        int cc = n*16 + lr;
        float s = 0.f, ss = 0.f;
        #pragma unroll
        for (int j = 0; j < 4; ++j){
            int ml = wv*16 + lg*4 + j;
            unsigned int b = ((unsigned int)(ml*256 + cc*2)) ^ ((unsigned int)((ml >> 2) & 3) << 5);
            float h = bf2f(*(const unsigned short*)(smem + b));
            float t = bf2f(*(const unsigned short*)(smem + 32768 + b));
            float v = acc[n][j] * (1.f + 0.5f*(h + t)) + res[n*4 + j];
            *(unsigned short*)(smem + b) = f2bf(v);   // single reader=writer
            s += v; ss += v*v;
        }
        s  += __shfl_xor(s, 16);  s  += __shfl_xor(s, 32);
        ss += __shfl_xor(ss, 16); ss += __shfl_xor(ss, 32);
        if (lane < 16){
            atomicAdd(&red[cc], s);
            atomicAdd(&red[CH + cc], ss);
        }
    }
    __syncthreads();                                   // B4
    // ---- coalesced readback + 16B stores of bf16 VB (4-seg x 256B) ----
    #pragma unroll
    for (int i = 0; i < 4; ++i){
        int g = tid + i*512;
        int r = g >> 4, c16 = g & 15;
        unsigned int b = ((unsigned int)(r*256 + c16*16)) ^ ((unsigned int)((r >> 2) & 3) << 5);
        uint4 o = *(const uint4*)(smem + b);
        *(uint4*)(VB + (size_t)(e0 + r)*CH + c16*8) = o;
    }
    if (tid < 256) atomicAdd(&sums[(blockIdx.x & 255)*256 + tid], red[tid]);
}

// ---------------------------------------------------------------------------
// k3: reduce 256 slots -> per-channel scale/shift (sb)
// ---------------------------------------------------------------------------
__global__ __launch_bounds__(128) void k3_stats(
        const float* __restrict__ sums, const float* __restrict__ gamma,
        const float* __restrict__ beta, float* __restrict__ sb, float invE){
    int c = threadIdx.x;
    float s = 0.f, ss = 0.f;
    for (int i = 0; i < 256; ++i){ s += sums[i*256 + c]; ss += sums[i*256 + CH + c]; }
    float mean = s * invE;
    float var = ss * invE - mean*mean;     // biased variance (matches reference)
    float inv = rsqrtf(var + 1e-5f);
    float sc = gamma[c] * inv;
    sb[c] = sc;
    sb[CH + c] = beta[c] - mean * sc;
}

// ---------------------------------------------------------------------------
// kE1: out_f32 = relu(vb*scale + shift); 8 elems/thread (proven ~90us)
// ---------------------------------------------------------------------------
__global__ __launch_bounds__(256) void kE1(
        const unsigned short* __restrict__ vb, const float* __restrict__ sb,
        float* __restrict__ out, int n8){
    int i = blockIdx.x * 256 + threadIdx.x;
    int stride = gridDim.x * 256;
    const uint4* v8 = (const uint4*)vb;
    for (; i < n8; i += stride){
        uint4 v = v8[i];
        int c8 = (i & 15) * 8;
        float4 sc0 = *(const float4*)(sb + c8);
        float4 sc1 = *(const float4*)(sb + c8 + 4);
        float4 sh0 = *(const float4*)(sb + CH + c8);
        float4 sh1 = *(const float4*)(sb + CH + c8 + 4);
        float4 o0, o1;
        o0.x = fmaxf(fmaf(bf2f((unsigned short)(v.x & 0xffff)), sc0.x, sh0.x), 0.f);
        o0.y = fmaxf(fmaf(bf2f((unsigned short)(v.x >> 16)),    sc0.y, sh0.y), 0.f);
        o0.z = fmaxf(fmaf(bf2f((unsigned short)(v.y & 0xffff)), sc0.z, sh0.z), 0.f);
        o0.w = fmaxf(fmaf(bf2f((unsigned short)(v.y >> 16)),    sc0.w, sh0.w), 0.f);
        o1.x = fmaxf(fmaf(bf2f((unsigned short)(v.z & 0xffff)), sc1.x, sh1.x), 0.f);
        o1.y = fmaxf(fmaf(bf2f((unsigned short)(v.z >> 16)),    sc1.y, sh1.y), 0.f);
        o1.z = fmaxf(fmaf(bf2f((unsigned short)(v.w & 0xffff)), sc1.z, sh1.z), 0.f);
        o1.w = fmaxf(fmaf(bf2f((unsigned short)(v.w >> 16)),    sc1.w, sh1.w), 0.f);
        *(float4*)(out + (size_t)i*8)     = o0;
        *(float4*)(out + (size_t)i*8 + 4) = o1;
    }
}

extern "C" void kernel_launch(void* const* d_in, const int* in_sizes, int n_in,
                              void* d_out, int out_size, void* d_ws, size_t ws_size,
                              hipStream_t stream) {
    const float* x      = (const float*)d_in[0];
    const int*   eidx   = (const int*)d_in[1];
    const float* ea     = (const float*)d_in[2];
    const float* w_self = (const float*)d_in[4];
    const float* w_h    = (const float*)d_in[5];
    const float* w_t    = (const float*)d_in[6];
    const float* gamma  = (const float*)d_in[7];
    const float* beta   = (const float*)d_in[8];
    float* out = (float*)d_out;

    const int N = in_sizes[0] / CH;     // 40000
    const int E = in_sizes[3];          // 640000

    // workspace carve-up (~185 MB total — proven to fit since R5):
    float* sums = (float*)d_ws;                          // 256*256 f32
    float* sb   = sums + 256*256;                        // 256 f32
    unsigned short* wT = (unsigned short*)(sb + 256);    // 3*128*128 bf16
    unsigned short* H  = wT + 3*CH*CH;                   // N*128 bf16
    unsigned short* T  = H + (size_t)N*CH;               // N*128 bf16
    unsigned short* VB = T + (size_t)N*CH;               // E*128 bf16 pre-BN

    k0_prep<<<256, 256, 0, stream>>>(w_self, w_h, w_t, wT, sums);
    k1_ht  <<<(N + 127)/128, 512, 0, stream>>>(x, wT, H, T, N);
    k2v    <<<E/128, 512, 0, stream>>>(ea, eidx, wT, H, T, VB, sums, E);
    k3_stats<<<1, 128, 0, stream>>>(sums, gamma, beta, sb, 1.0f/(float)E);
    kE1    <<<2048, 256, 0, stream>>>(VB, sb, out, E*CH/8);
}

// Round 9
// 359.804 us; speedup vs baseline: 1.5250x; 1.0673x over previous
//
#include <hip/hip_runtime.h>
#include <cstdint>
#include <cstddef>

#define CH 128

typedef __attribute__((ext_vector_type(8))) short bf16x8;
typedef __attribute__((ext_vector_type(4))) float f32x4;

__device__ __forceinline__ unsigned short f2bf(float x){
    unsigned int u = __float_as_uint(x);
    u = (u + 0x7FFFu + ((u >> 16) & 1u)) >> 16;   // RNE
    return (unsigned short)u;
}
__device__ __forceinline__ float bf2f(unsigned short b){
    return __uint_as_float(((unsigned int)b) << 16);
}

// ---------------------------------------------------------------------------
// k0: transpose+convert weights to bf16 wT[mat][n][k]; zero sums[256*256].
// ---------------------------------------------------------------------------
__global__ __launch_bounds__(256) void k0_prep(
        const float* __restrict__ w_self, const float* __restrict__ w_h,
        const float* __restrict__ w_t, unsigned short* __restrict__ wT,
        float* __restrict__ sums){
    int t = blockIdx.x * 256 + threadIdx.x;
    if (t < 256*256) sums[t] = 0.f;
    if (t < 3*CH*CH){
        int mat = t / (CH*CH);
        int r = t - mat*(CH*CH);
        int k = r >> 7, n = r & 127;
        const float* w = (mat == 0) ? w_self : ((mat == 1) ? w_h : w_t);
        wT[mat*CH*CH + n*CH + k] = f2bf(w[k*CH + n]);
    }
}

// ---------------------------------------------------------------------------
// k1: H = x @ w_h, T = x @ w_t  (bf16 out, f32 MFMA accumulate). Proven R0-R8.
// ---------------------------------------------------------------------------
__global__ __launch_bounds__(512) void k1_ht(
        const float* __restrict__ x, const unsigned short* __restrict__ wT,
        unsigned short* __restrict__ H, unsigned short* __restrict__ T, int N){
    __shared__ __align__(16) unsigned char smem[98304];
    const int tid = threadIdx.x;
    const int m0 = blockIdx.x * 128;
    #pragma unroll
    for (int i = 0; i < 8; ++i){
        int g = tid + i*512;
        int row = g >> 5, col4 = (g & 31) * 4;
        int rg = m0 + row; rg = rg < N ? rg : N-1;
        float4 v = *(const float4*)(x + (size_t)rg*CH + col4);
        unsigned int lo = (unsigned int)f2bf(v.x) | ((unsigned int)f2bf(v.y) << 16);
        unsigned int hi = (unsigned int)f2bf(v.z) | ((unsigned int)f2bf(v.w) << 16);
        unsigned int b = ((unsigned int)(row*256 + col4*2)) ^ ((unsigned int)(row & 7) << 4);
        *(uint2*)(smem + b) = make_uint2(lo, hi);
    }
    #pragma unroll
    for (int m = 0; m < 2; ++m){
        const unsigned short* src = wT + (m+1)*CH*CH;
        unsigned char* dst = smem + 32768 + m*32768;
        #pragma unroll
        for (int i = 0; i < 4; ++i){
            int g = tid + i*512;
            int n = g >> 4, k8 = (g & 15) * 8;
            uint4 v = *(const uint4*)(src + n*CH + k8);
            unsigned int b = ((unsigned int)(n*256 + k8*2)) ^ ((unsigned int)(n & 7) << 4);
            *(uint4*)(dst + b) = v;
        }
    }
    __syncthreads();
    const int lane = tid & 63, wv = tid >> 6;
    const int lr = lane & 15, lg = lane >> 4;
    f32x4 accH[8], accT[8];
    #pragma unroll
    for (int n = 0; n < 8; ++n){ accH[n] = (f32x4){0.f,0.f,0.f,0.f}; accT[n] = (f32x4){0.f,0.f,0.f,0.f}; }
    #pragma unroll
    for (int kk = 0; kk < 4; ++kk){
        int arow = wv*16 + lr;
        unsigned int ab = ((unsigned int)(arow*256 + kk*64 + lg*16)) ^ ((unsigned int)(arow & 7) << 4);
        bf16x8 a = *(const bf16x8*)(smem + ab);
        #pragma unroll
        for (int n = 0; n < 8; ++n){
            int cc = n*16 + lr;
            unsigned int bb = ((unsigned int)(cc*256 + kk*64 + lg*16)) ^ ((unsigned int)(cc & 7) << 4);
            bf16x8 bh = *(const bf16x8*)(smem + 32768 + bb);
            bf16x8 bt = *(const bf16x8*)(smem + 65536 + bb);
            accH[n] = __builtin_amdgcn_mfma_f32_16x16x32_bf16(a, bh, accH[n], 0, 0, 0);
            accT[n] = __builtin_amdgcn_mfma_f32_16x16x32_bf16(a, bt, accT[n], 0, 0, 0);
        }
    }
    #pragma unroll
    for (int n = 0; n < 8; ++n){
        int cc = n*16 + lr;
        #pragma unroll
        for (int j = 0; j < 4; ++j){
            int mr = m0 + wv*16 + lg*4 + j;
            if (mr < N){
                H[(size_t)mr*CH + cc] = f2bf(accH[n][j]);
                T[(size_t)mr*CH + cc] = f2bf(accT[n][j]);
            }
        }
    }
}

// ---------------------------------------------------------------------------
// k2v v2: R8's winning kernel + explicit load-phase schedule:
//   issue eidx -> wv4 -> eav -> gathers (vmcnt waits only eidx);
//   wv4->LDS early (regs die, peak ~96 live, no spill under 128 cap);
//   raw lgkm-only barriers so gathers stay in flight across B1+MFMA+res,
//   first waited at redistribute (compiler vmcnt on hv/tv use).
// ---------------------------------------------------------------------------
__global__ __launch_bounds__(512, 4) void k2v(
        const float* __restrict__ ea, const int* __restrict__ eidx,
        const unsigned short* __restrict__ wT,
        const unsigned short* __restrict__ Hm, const unsigned short* __restrict__ Tm,
        unsigned short* __restrict__ VB, float* __restrict__ sums, int E){
    __shared__ __align__(16) unsigned char smem[66560];
    float* red = (float*)(smem + 65536);
    const int tid = threadIdx.x;
    const int e0 = blockIdx.x * 128;
    if (tid < 256) red[tid] = 0.f;

    // ---- phase 0: edge-index loads (gather addresses depend on these) ----
    int ri4[4], ci4[4];
    #pragma unroll
    for (int i = 0; i < 4; ++i){
        int r = (tid + i*512) >> 4;
        ri4[i] = eidx[e0 + r];
        ci4[i] = eidx[E + e0 + r];
    }
    __builtin_amdgcn_sched_barrier(0);
    // ---- phase 1: weight tile loads (L2-hot) ----
    uint4 wv4[4];
    #pragma unroll
    for (int i = 0; i < 4; ++i){
        int g = tid + i*512;
        int n = g >> 4, k8 = (g & 15)*8;
        wv4[i] = *(const uint4*)(wT + n*CH + k8);
    }
    __builtin_amdgcn_sched_barrier(0);
    // ---- phase 2: streaming ea loads (HBM, hidden under later phases) ----
    float4 eav[8];
    #pragma unroll
    for (int i = 0; i < 8; ++i){
        int g = tid + i*512;
        int row = g >> 5, col4 = (g & 31)*4;
        eav[i] = *(const float4*)(ea + (size_t)(e0+row)*CH + col4);
    }
    __builtin_amdgcn_sched_barrier(0);
    // ---- phase 3: issue H/T gathers (waits only eidx: in-order vmcnt) ----
    uint4 hv[4], tv[4];
    #pragma unroll
    for (int i = 0; i < 4; ++i){
        int c = (tid + i*512) & 15;
        hv[i] = *(const uint4*)(Hm + (size_t)ri4[i]*CH + c*8);
        tv[i] = *(const uint4*)(Tm + (size_t)ci4[i]*CH + c*8);
    }
    __builtin_amdgcn_sched_barrier(0);
    // ---- phase 4: wv4 -> B LDS (wv4 regs die; eav+gathers stay in flight) --
    #pragma unroll
    for (int i = 0; i < 4; ++i){
        int g = tid + i*512;
        int n = g >> 4, k8 = (g & 15)*8;
        unsigned int b = ((unsigned int)(n*256 + k8*2)) ^ ((unsigned int)(n & 7) << 4);
        *(uint4*)(smem + 32768 + b) = wv4[i];
    }
    __builtin_amdgcn_sched_barrier(0);
    // ---- phase 5: stage ea -> bf16 A LDS (vmcnt(8): gathers stay out) ----
    #pragma unroll
    for (int i = 0; i < 8; ++i){
        int g = tid + i*512;
        int row = g >> 5, col4 = (g & 31)*4;
        float4 v = eav[i];
        unsigned int lo = (unsigned int)f2bf(v.x) | ((unsigned int)f2bf(v.y) << 16);
        unsigned int hi = (unsigned int)f2bf(v.z) | ((unsigned int)f2bf(v.w) << 16);
        unsigned int b = ((unsigned int)(row*256 + col4*2)) ^ ((unsigned int)(row & 7) << 4);
        *(uint2*)(smem + b) = make_uint2(lo, hi);
    }
    // B1: LDS-only barrier (gathers NOT drained)
    asm volatile("s_waitcnt lgkmcnt(0)\n\ts_barrier" ::: "memory");

    const int lane = tid & 63, wv = tid >> 6;
    const int lr = lane & 15, lg = lane >> 4;
    f32x4 acc[8];
    #pragma unroll
    for (int n = 0; n < 8; ++n) acc[n] = (f32x4){0.f,0.f,0.f,0.f};
    #pragma unroll
    for (int kk = 0; kk < 4; ++kk){
        int arow = wv*16 + lr;
        unsigned int ab = ((unsigned int)(arow*256 + kk*64 + lg*16)) ^ ((unsigned int)(arow & 7) << 4);
        bf16x8 a = *(const bf16x8*)(smem + ab);
        #pragma unroll
        for (int n = 0; n < 8; ++n){
            int cc = n*16 + lr;
            unsigned int bb = ((unsigned int)(cc*256 + kk*64 + lg*16)) ^ ((unsigned int)(cc & 7) << 4);
            bf16x8 bw = *(const bf16x8*)(smem + 32768 + bb);
            acc[n] = __builtin_amdgcn_mfma_f32_16x16x32_bf16(a, bw, acc[n], 0, 0, 0);
        }
    }
    // ---- residual: read staged ea (bf16) before overwrite ----
    float res[32];
    #pragma unroll
    for (int n = 0; n < 8; ++n){
        int cc = n*16 + lr;
        #pragma unroll
        for (int j = 0; j < 4; ++j){
            int ml = wv*16 + lg*4 + j;
            unsigned int b = ((unsigned int)(ml*256 + cc*2)) ^ ((unsigned int)(ml & 7) << 4);
            res[n*4 + j] = bf2f(*(const unsigned short*)(smem + b));
        }
    }
    asm volatile("s_waitcnt lgkmcnt(0)\n\ts_barrier" ::: "memory");   // B2
    // ---- redistribute gathers (compiler vmcnt waits hv/tv HERE, after
    //      ~B1+MFMA+res of flight time) ----
    #pragma unroll
    for (int i = 0; i < 4; ++i){
        int g = tid + i*512;
        int r = g >> 4, c = g & 15;
        unsigned int b = ((unsigned int)(r*256 + c*16)) ^ ((unsigned int)((r >> 2) & 3) << 5);
        *(uint4*)(smem + b) = hv[i];
        *(uint4*)(smem + 32768 + b) = tv[i];
    }
    asm volatile("s_waitcnt lgkmcnt(0)\n\ts_barrier" ::: "memory");   // B3
    // ---- epilogue: v = o0*(1+0.5(h+t)) + res; stats; bf16 v in-place ----
    #pragma unroll
    for (int n = 0; n < 8; ++n){
        int cc = n*16 + lr;
        float s = 0.f, ss = 0.f;
        #pragma unroll
        for (int j = 0; j < 4; ++j){
            int ml = wv*16 + lg*4 + j;
            unsigned int b = ((unsigned int)(ml*256 + cc*2)) ^ ((unsigned int)((ml >> 2) & 3) << 5);
            float h = bf2f(*(const unsigned short*)(smem + b));
            float t = bf2f(*(const unsigned short*)(smem + 32768 + b));
            float v = acc[n][j] * (1.f + 0.5f*(h + t)) + res[n*4 + j];
            *(unsigned short*)(smem + b) = f2bf(v);   // single reader=writer
            s += v; ss += v*v;
        }
        s  += __shfl_xor(s, 16);  s  += __shfl_xor(s, 32);
        ss += __shfl_xor(ss, 16); ss += __shfl_xor(ss, 32);
        if (lane < 16){
            atomicAdd(&red[cc], s);
            atomicAdd(&red[CH + cc], ss);
        }
    }
    asm volatile("s_waitcnt lgkmcnt(0)\n\ts_barrier" ::: "memory");   // B4
    // ---- coalesced readback + 16B stores of bf16 VB ----
    #pragma unroll
    for (int i = 0; i < 4; ++i){
        int g = tid + i*512;
        int r = g >> 4, c16 = g & 15;
        unsigned int b = ((unsigned int)(r*256 + c16*16)) ^ ((unsigned int)((r >> 2) & 3) << 5);
        uint4 o = *(const uint4*)(smem + b);
        *(uint4*)(VB + (size_t)(e0 + r)*CH + c16*8) = o;
    }
    if (tid < 256) atomicAdd(&sums[(blockIdx.x & 255)*256 + tid], red[tid]);
}

// ---------------------------------------------------------------------------
// k3: reduce 256 slots -> per-channel scale/shift (sb)
// ---------------------------------------------------------------------------
__global__ __launch_bounds__(128) void k3_stats(
        const float* __restrict__ sums, const float* __restrict__ gamma,
        const float* __restrict__ beta, float* __restrict__ sb, float invE){
    int c = threadIdx.x;
    float s = 0.f, ss = 0.f;
    for (int i = 0; i < 256; ++i){ s += sums[i*256 + c]; ss += sums[i*256 + CH + c]; }
    float mean = s * invE;
    float var = ss * invE - mean*mean;     // biased variance (matches reference)
    float inv = rsqrtf(var + 1e-5f);
    float sc = gamma[c] * inv;
    sb[c] = sc;
    sb[CH + c] = beta[c] - mean * sc;
}

// ---------------------------------------------------------------------------
// kE1: out_f32 = relu(vb*scale + shift); 8 elems/thread (proven ~90us)
// ---------------------------------------------------------------------------
__global__ __launch_bounds__(256) void kE1(
        const unsigned short* __restrict__ vb, const float* __restrict__ sb,
        float* __restrict__ out, int n8){
    int i = blockIdx.x * 256 + threadIdx.x;
    int stride = gridDim.x * 256;
    const uint4* v8 = (const uint4*)vb;
    for (; i < n8; i += stride){
        uint4 v = v8[i];
        int c8 = (i & 15) * 8;
        float4 sc0 = *(const float4*)(sb + c8);
        float4 sc1 = *(const float4*)(sb + c8 + 4);
        float4 sh0 = *(const float4*)(sb + CH + c8);
        float4 sh1 = *(const float4*)(sb + CH + c8 + 4);
        float4 o0, o1;
        o0.x = fmaxf(fmaf(bf2f((unsigned short)(v.x & 0xffff)), sc0.x, sh0.x), 0.f);
        o0.y = fmaxf(fmaf(bf2f((unsigned short)(v.x >> 16)),    sc0.y, sh0.y), 0.f);
        o0.z = fmaxf(fmaf(bf2f((unsigned short)(v.y & 0xffff)), sc0.z, sh0.z), 0.f);
        o0.w = fmaxf(fmaf(bf2f((unsigned short)(v.y >> 16)),    sc0.w, sh0.w), 0.f);
        o1.x = fmaxf(fmaf(bf2f((unsigned short)(v.z & 0xffff)), sc1.x, sh1.x), 0.f);
        o1.y = fmaxf(fmaf(bf2f((unsigned short)(v.z >> 16)),    sc1.y, sh1.y), 0.f);
        o1.z = fmaxf(fmaf(bf2f((unsigned short)(v.w & 0xffff)), sc1.z, sh1.z), 0.f);
        o1.w = fmaxf(fmaf(bf2f((unsigned short)(v.w >> 16)),    sc1.w, sh1.w), 0.f);
        *(float4*)(out + (size_t)i*8)     = o0;
        *(float4*)(out + (size_t)i*8 + 4) = o1;
    }
}

extern "C" void kernel_launch(void* const* d_in, const int* in_sizes, int n_in,
                              void* d_out, int out_size, void* d_ws, size_t ws_size,
                              hipStream_t stream) {
    const float* x      = (const float*)d_in[0];
    const int*   eidx   = (const int*)d_in[1];
    const float* ea     = (const float*)d_in[2];
    const float* w_self = (const float*)d_in[4];
    const float* w_h    = (const float*)d_in[5];
    const float* w_t    = (const float*)d_in[6];
    const float* gamma  = (const float*)d_in[7];
    const float* beta   = (const float*)d_in[8];
    float* out = (float*)d_out;

    const int N = in_sizes[0] / CH;     // 40000
    const int E = in_sizes[3];          // 640000

    // workspace carve-up (~185 MB total — proven to fit since R5):
    float* sums = (float*)d_ws;                          // 256*256 f32
    float* sb   = sums + 256*256;                        // 256 f32
    unsigned short* wT = (unsigned short*)(sb + 256);    // 3*128*128 bf16
    unsigned short* H  = wT + 3*CH*CH;                   // N*128 bf16
    unsigned short* T  = H + (size_t)N*CH;               // N*128 bf16
    unsigned short* VB = T + (size_t)N*CH;               // E*128 bf16 pre-BN

    k0_prep<<<256, 256, 0, stream>>>(w_self, w_h, w_t, wT, sums);
    k1_ht  <<<(N + 127)/128, 512, 0, stream>>>(x, wT, H, T, N);
    k2v    <<<E/128, 512, 0, stream>>>(ea, eidx, wT, H, T, VB, sums, E);
    k3_stats<<<1, 128, 0, stream>>>(sums, gamma, beta, sb, 1.0f/(float)E);
    kE1    <<<2048, 256, 0, stream>>>(VB, sb, out, E*CH/8);
}